// Round 1
// baseline (1525.680 us; speedup 1.0000x reference)
//
#include <hip/hip_runtime.h>

namespace {

constexpr int NBATCH = 2048;
constexpr int NT     = 200;

// One wave (64 lanes) handles one batch element's full 200-step backward
// Riccati recursion. Single-wave blocks: no __syncthreads needed (DS ops from
// one wave execute in order; compiler preserves may-alias LDS ordering).
// LDS = 20384 B -> 8 blocks/CU -> all 2048 blocks co-resident.
__global__ __launch_bounds__(64, 2) void lqr_kernel(
    const float* __restrict__ gA,   // [B,32,32]
    const float* __restrict__ gB,   // [B,32,8]
    const float* __restrict__ gQ,   // [B,32,32]
    const float* __restrict__ gR,   // [B,8,8]
    const float* __restrict__ gG,   // [B,201,32]
    float* __restrict__ outK,       // [T,B,8,32]
    float* __restrict__ outk)       // [T,B,8]
{
    __shared__ float smem[5096];
    float* const sA   = smem;          // [32][32] row-major
    float* const sV   = smem + 1024;   // [32][32] running V
    float* const sWt  = smem + 2048;   // [32][32]: Wt[j][i] = (A^T V)[i][j]
    float* const sABK = smem + 3072;   // [32][32] A - B*Kg
    float* const sBp  = smem + 4096;   // [32][9]  B padded (kills column-read conflicts)
    float* const sBtV = smem + 4384;   // [8][36]  B^T V (pad 36: conflict-free row reads); aliased as Kg later
    float* const sM2  = smem + 4672;   // [8][32]  BtV*A
    float* const sGJ  = smem + 4928;   // [8][16]  Gauss-Jordan [Vuu | I]
    float* const svv  = smem + 5056;   // [32] running v
    float* const sbtv = smem + 5088;   // [8]  B^T v

    const int lane = threadIdx.x;      // 0..63
    const int b    = blockIdx.x;
    const int ig   = lane >> 3;        // 0..7 (row group / u index)
    const int kg   = lane & 7;         // 0..7 (col group)
    const int i0   = ig << 2;
    const int k0   = kg << 2;
    const int jj   = lane & 31;

    const float* __restrict__ Ab = gA + (size_t)b * 1024;
    const float* __restrict__ Bb = gB + (size_t)b * 256;
    const float* __restrict__ Qb = gQ + (size_t)b * 1024;
    const float* __restrict__ Gb = gG + (size_t)b * (201 * 32);

    // ---------------- one-time staging ----------------
    #pragma unroll
    for (int m = 0; m < 4; ++m) {
        float4 a4 = reinterpret_cast<const float4*>(Ab)[lane + 64 * m];
        float4 q4 = reinterpret_cast<const float4*>(Qb)[lane + 64 * m];
        reinterpret_cast<float4*>(sA)[lane + 64 * m] = a4;
        reinterpret_cast<float4*>(sV)[lane + 64 * m] = q4;   // V0 = Q
    }
    {
        float4 b4 = reinterpret_cast<const float4*>(Bb)[lane];
        const int fb = lane * 4;   // flat index into [32][8]
        sBp[((fb + 0) >> 3) * 9 + ((fb + 0) & 7)] = b4.x;
        sBp[((fb + 1) >> 3) * 9 + ((fb + 1) & 7)] = b4.y;
        sBp[((fb + 2) >> 3) * 9 + ((fb + 2) & 7)] = b4.z;
        sBp[((fb + 3) >> 3) * 9 + ((fb + 3) & 7)] = b4.w;
    }
    const float rreg = gR[(size_t)b * 64 + lane];   // R[ig][kg]

    // Q held in registers for the whole kernel:
    //   Qcol[m] = Q[m][jj]  (column jj; Q is exactly symmetric -> Q*g via column dots, coalesced loads)
    //   qr0..qr3 = Q[i0+r][k0:k0+4] (this lane's output-tile addend)
    float Qcol[32];
    #pragma unroll
    for (int m = 0; m < 32; ++m) Qcol[m] = Qb[m * 32 + jj];
    const float4 qr0 = *reinterpret_cast<const float4*>(&Qb[(i0 + 0) * 32 + k0]);
    const float4 qr1 = *reinterpret_cast<const float4*>(&Qb[(i0 + 1) * 32 + k0]);
    const float4 qr2 = *reinterpret_cast<const float4*>(&Qb[(i0 + 2) * 32 + k0]);
    const float4 qr3 = *reinterpret_cast<const float4*>(&Qb[(i0 + 3) * 32 + k0]);

    {   // v0 = Q * goals[:, T, :]
        const float* __restrict__ gl = Gb + 200 * 32;
        float t = 0.f;
        #pragma unroll
        for (int m = 0; m < 32; ++m) t += Qcol[m] * gl[m];
        if (lane < 32) svv[jj] = t;
    }

    for (int c = 0; c < NT; ++c) {
        const int step = NT - 1 - c;
        const float* __restrict__ grow = Gb + step * 32;   // uniform -> scalar loads

        // ---- t2 = (Q * goal_step)[jj]  (independent of step state; issued early)
        float t2 = 0.f;
        #pragma unroll
        for (int m = 0; m < 32; ++m) t2 += Qcol[m] * grow[m];

        // ================= P1: W = A^T V (stored transposed), BtV = B^T V, btv = B^T v
        {
            float w00=0,w01=0,w02=0,w03=0, w10=0,w11=0,w12=0,w13=0;
            float w20=0,w21=0,w22=0,w23=0, w30=0,w31=0,w32=0,w33=0;
            float bt0=0,bt1=0,bt2=0,bt3=0, bdot=0;
            #pragma unroll
            for (int j = 0; j < 32; ++j) {
                const float4 av = *reinterpret_cast<const float4*>(&sA[j * 32 + i0]); // A[j][i0:4]
                const float4 vv = *reinterpret_cast<const float4*>(&sV[j * 32 + k0]); // V[j][k0:4]
                const float  bj = sBp[j * 9 + ig];                                    // B[j][ig]
                const float  vj = svv[j];
                w00 += av.x*vv.x; w01 += av.x*vv.y; w02 += av.x*vv.z; w03 += av.x*vv.w;
                w10 += av.y*vv.x; w11 += av.y*vv.y; w12 += av.y*vv.z; w13 += av.y*vv.w;
                w20 += av.z*vv.x; w21 += av.z*vv.y; w22 += av.z*vv.z; w23 += av.z*vv.w;
                w30 += av.w*vv.x; w31 += av.w*vv.y; w32 += av.w*vv.z; w33 += av.w*vv.w;
                bt0 += bj*vv.x;  bt1 += bj*vv.y;  bt2 += bj*vv.z;  bt3 += bj*vv.w;
                bdot += bj * vj;
            }
            // Wt[k][i] = W[i][k]
            *reinterpret_cast<float4*>(&sWt[(k0 + 0) * 32 + i0]) = make_float4(w00, w10, w20, w30);
            *reinterpret_cast<float4*>(&sWt[(k0 + 1) * 32 + i0]) = make_float4(w01, w11, w21, w31);
            *reinterpret_cast<float4*>(&sWt[(k0 + 2) * 32 + i0]) = make_float4(w02, w12, w22, w32);
            *reinterpret_cast<float4*>(&sWt[(k0 + 3) * 32 + i0]) = make_float4(w03, w13, w23, w33);
            *reinterpret_cast<float4*>(&sBtV[ig * 36 + k0]) = make_float4(bt0, bt1, bt2, bt3);
            if (kg == 0) sbtv[ig] = bdot;
        }

        // ================= P2: M2 = BtV*A and Vuu = BtV*B + R (fused), then Gauss-Jordan invert
        {
            float m20=0,m21=0,m22=0,m23=0;
            float vu = rreg;
            #pragma unroll
            for (int j = 0; j < 32; ++j) {
                const float  btvj = sBtV[ig * 36 + j];                                 // conflict-free (pad 36)
                const float4 a4   = *reinterpret_cast<const float4*>(&sA[j * 32 + k0]); // A[j][k0:4] broadcast
                const float  bk   = sBp[j * 9 + kg];                                    // B[j][kg] conflict-free (pad 9)
                m20 += btvj * a4.x; m21 += btvj * a4.y; m22 += btvj * a4.z; m23 += btvj * a4.w;
                vu  += btvj * bk;
            }
            *reinterpret_cast<float4*>(&sM2[ig * 32 + k0]) = make_float4(m20, m21, m22, m23);
            sGJ[ig * 16 + kg]     = vu;                       // Vuu[ig][kg]
            sGJ[ig * 16 + 8 + kg] = (ig == kg) ? 1.f : 0.f;   // identity

            // Gauss-Jordan on [Vuu | I]; Vuu is PD with diag >= 1 (R = I + PSD) -> no pivoting.
            #pragma unroll
            for (int p = 0; p < 8; ++p) {
                const float piv  = sGJ[p * 16 + p];
                const float rp   = 1.0f / piv;
                const float mrp  = sGJ[ig * 16 + p];
                const float pc   = sGJ[p * 16 + kg];
                const float pc8  = sGJ[p * 16 + 8 + kg];
                const float cur  = sGJ[ig * 16 + kg];
                const float cur8 = sGJ[ig * 16 + 8 + kg];
                const float f    = mrp * rp;
                const float nv   = (ig == p) ? pc * rp  : cur  - f * pc;
                const float nv8  = (ig == p) ? pc8 * rp : cur8 - f * pc8;
                sGJ[ig * 16 + kg]     = nv;
                sGJ[ig * 16 + 8 + kg] = nv8;
            }
        }

        // ================= P3: Kg = Vuu_inv * M2 ; kf = Vuu_inv * (B^T v) ; write outputs
        float* const sKg = sBtV;   // alias: BtV dead after P2
        {
            float ka0=0,ka1=0,ka2=0,ka3=0, kfv=0;
            #pragma unroll
            for (int u2 = 0; u2 < 8; ++u2) {
                const float  w  = sGJ[ig * 16 + 8 + u2];  // inv[ig][u2]
                const float4 m4 = *reinterpret_cast<const float4*>(&sM2[u2 * 32 + k0]);
                const float  bt = sbtv[u2];
                ka0 += w * m4.x; ka1 += w * m4.y; ka2 += w * m4.z; ka3 += w * m4.w;
                kfv += w * bt;
            }
            *reinterpret_cast<float4*>(&sKg[ig * 36 + k0]) = make_float4(ka0, ka1, ka2, ka3);
            const size_t ob = (size_t)step * NBATCH + b;
            *reinterpret_cast<float4*>(&outK[ob * 256 + ig * 32 + k0]) = make_float4(ka0, ka1, ka2, ka3);
            if (kg == 0) outk[ob * 8 + ig] = kfv;
        }

        // ================= P4: ABK = A - B*Kg
        {
            const float4 a0 = *reinterpret_cast<const float4*>(&sA[(i0 + 0) * 32 + k0]);
            const float4 a1 = *reinterpret_cast<const float4*>(&sA[(i0 + 1) * 32 + k0]);
            const float4 a2 = *reinterpret_cast<const float4*>(&sA[(i0 + 2) * 32 + k0]);
            const float4 a3 = *reinterpret_cast<const float4*>(&sA[(i0 + 3) * 32 + k0]);
            float b00=a0.x,b01=a0.y,b02=a0.z,b03=a0.w;
            float b10=a1.x,b11=a1.y,b12=a1.z,b13=a1.w;
            float b20=a2.x,b21=a2.y,b22=a2.z,b23=a2.w;
            float b30=a3.x,b31=a3.y,b32=a3.z,b33=a3.w;
            #pragma unroll
            for (int u = 0; u < 8; ++u) {
                const float4 kg4 = *reinterpret_cast<const float4*>(&sKg[u * 36 + k0]); // Kg[u][k0:4] broadcast
                const float br0 = sBp[(i0 + 0) * 9 + u];
                const float br1 = sBp[(i0 + 1) * 9 + u];
                const float br2 = sBp[(i0 + 2) * 9 + u];
                const float br3 = sBp[(i0 + 3) * 9 + u];
                b00 -= br0*kg4.x; b01 -= br0*kg4.y; b02 -= br0*kg4.z; b03 -= br0*kg4.w;
                b10 -= br1*kg4.x; b11 -= br1*kg4.y; b12 -= br1*kg4.z; b13 -= br1*kg4.w;
                b20 -= br2*kg4.x; b21 -= br2*kg4.y; b22 -= br2*kg4.z; b23 -= br2*kg4.w;
                b30 -= br3*kg4.x; b31 -= br3*kg4.y; b32 -= br3*kg4.z; b33 -= br3*kg4.w;
            }
            *reinterpret_cast<float4*>(&sABK[(i0 + 0) * 32 + k0]) = make_float4(b00, b01, b02, b03);
            *reinterpret_cast<float4*>(&sABK[(i0 + 1) * 32 + k0]) = make_float4(b10, b11, b12, b13);
            *reinterpret_cast<float4*>(&sABK[(i0 + 2) * 32 + k0]) = make_float4(b20, b21, b22, b23);
            *reinterpret_cast<float4*>(&sABK[(i0 + 3) * 32 + k0]) = make_float4(b30, b31, b32, b33);
        }

        // ================= P5: V = W*ABK + Q ; v = ABK^T v + Q*goal
        {
            float v00=0,v01=0,v02=0,v03=0, v10=0,v11=0,v12=0,v13=0;
            float v20=0,v21=0,v22=0,v23=0, v30=0,v31=0,v32=0,v33=0;
            #pragma unroll
            for (int j = 0; j < 32; ++j) {
                const float4 w4 = *reinterpret_cast<const float4*>(&sWt[j * 32 + i0]);  // W[i0:4][j]
                const float4 a4 = *reinterpret_cast<const float4*>(&sABK[j * 32 + k0]); // ABK[j][k0:4]
                v00 += w4.x*a4.x; v01 += w4.x*a4.y; v02 += w4.x*a4.z; v03 += w4.x*a4.w;
                v10 += w4.y*a4.x; v11 += w4.y*a4.y; v12 += w4.y*a4.z; v13 += w4.y*a4.w;
                v20 += w4.z*a4.x; v21 += w4.z*a4.y; v22 += w4.z*a4.z; v23 += w4.z*a4.w;
                v30 += w4.w*a4.x; v31 += w4.w*a4.y; v32 += w4.w*a4.z; v33 += w4.w*a4.w;
            }
            v00 += qr0.x; v01 += qr0.y; v02 += qr0.z; v03 += qr0.w;
            v10 += qr1.x; v11 += qr1.y; v12 += qr1.z; v13 += qr1.w;
            v20 += qr2.x; v21 += qr2.y; v22 += qr2.z; v23 += qr2.w;
            v30 += qr3.x; v31 += qr3.y; v32 += qr3.z; v33 += qr3.w;
            *reinterpret_cast<float4*>(&sV[(i0 + 0) * 32 + k0]) = make_float4(v00, v01, v02, v03);
            *reinterpret_cast<float4*>(&sV[(i0 + 1) * 32 + k0]) = make_float4(v10, v11, v12, v13);
            *reinterpret_cast<float4*>(&sV[(i0 + 2) * 32 + k0]) = make_float4(v20, v21, v22, v23);
            *reinterpret_cast<float4*>(&sV[(i0 + 3) * 32 + k0]) = make_float4(v30, v31, v32, v33);

            // v_new[jj] = sum_k ABK[k][jj]*v[k] + t2 ; all reads precede the masked write (in-order DS)
            float t1 = 0.f;
            #pragma unroll
            for (int m = 0; m < 32; ++m) t1 += sABK[m * 32 + jj] * svv[m];
            if (lane < 32) svv[jj] = t1 + t2;
        }
    }
}

}  // namespace

extern "C" void kernel_launch(void* const* d_in, const int* in_sizes, int n_in,
                              void* d_out, int out_size, void* d_ws, size_t ws_size,
                              hipStream_t stream) {
    const float* A = (const float*)d_in[0];
    const float* B = (const float*)d_in[1];
    const float* Q = (const float*)d_in[2];
    const float* R = (const float*)d_in[3];
    const float* G = (const float*)d_in[4];
    float* outK = (float*)d_out;
    float* outk = outK + (size_t)NT * NBATCH * 8 * 32;   // 104,857,600
    lqr_kernel<<<dim3(NBATCH), dim3(64), 0, stream>>>(A, B, Q, R, G, outK, outk);
}

// Round 4
// 1313.090 us; speedup vs baseline: 1.1619x; 1.1619x over previous
//
#include <hip/hip_runtime.h>

namespace {

constexpr int NBATCH = 2048;
constexpr int NT     = 200;

typedef __bf16 bf16x8 __attribute__((ext_vector_type(8)));
typedef float  f32x16 __attribute__((ext_vector_type(16)));

struct Frag3 { bf16x8 h, m, l; };

// Exact 3-way split of fp32 into bf16 hi/mid/lo with RTNE at every stage.
// Residuals r1 = v - hi, r2 = r1 - mid are exact in fp32 (Sterbenz); with RTNE
// |r1| <= 2^-8|v|, |r2| <= 2^-16|v|, and hi+mid+lo represents v to ~2^-24 rel.
__device__ inline Frag3 split3_8(const float f[8]) {
  union { unsigned short us[8]; bf16x8 v; } uh, um, ul;
  #pragma unroll
  for (int e = 0; e < 8; ++e) {
    const float v = f[e];
    unsigned int hb = __float_as_uint(v);
    hb += 0x7FFFu + ((hb >> 16) & 1u);       // RTNE to bf16
    hb &= 0xFFFF0000u;
    const float r1 = v - __uint_as_float(hb);          // exact
    unsigned int mb = __float_as_uint(r1);
    mb += 0x7FFFu + ((mb >> 16) & 1u);
    mb &= 0xFFFF0000u;
    const float r2 = r1 - __uint_as_float(mb);         // exact
    unsigned int lb = __float_as_uint(r2);
    lb += 0x7FFFu + ((lb >> 16) & 1u);
    uh.us[e] = (unsigned short)(hb >> 16);
    um.us[e] = (unsigned short)(mb >> 16);
    ul.us[e] = (unsigned short)(lb >> 16);
  }
  Frag3 r; r.h = uh.v; r.m = um.v; r.l = ul.v; return r;
}

// Cross-term group: lh, hl, mm (~2^-16|D|) then mh, hm (~2^-8|D|).
// Accumulated SEPARATELY from the hh group so every rounding here happens at
// ulp(2^-7|D|), not ulp(|D|). Dropped ml+lm+ll ~ 2.4e-8|D| (~0.2 fp32 ulp).
__device__ inline f32x16 mm_lo(f32x16 acc, const Frag3& a, const Frag3& b) {
  acc = __builtin_amdgcn_mfma_f32_32x32x16_bf16(a.l, b.h, acc, 0, 0, 0);
  acc = __builtin_amdgcn_mfma_f32_32x32x16_bf16(a.h, b.l, acc, 0, 0, 0);
  acc = __builtin_amdgcn_mfma_f32_32x32x16_bf16(a.m, b.m, acc, 0, 0, 0);
  acc = __builtin_amdgcn_mfma_f32_32x32x16_bf16(a.m, b.h, acc, 0, 0, 0);
  acc = __builtin_amdgcn_mfma_f32_32x32x16_bf16(a.h, b.m, acc, 0, 0, 0);
  return acc;
}
__device__ inline f32x16 mm_hh(f32x16 acc, const Frag3& a, const Frag3& b) {
  return __builtin_amdgcn_mfma_f32_32x32x16_bf16(a.h, b.h, acc, 0, 0, 0);
}

// One wave = one batch element, full 200-step backward Riccati recursion.
// MFMA 32x32x16_bf16 layouts (CDNA4, verified numerically in rounds 2-3):
//   A-frag: lane holds A[l&31][16h + 8*(l>>5) + e], e=0..7
//   B-frag: lane holds B[16h + 8*(l>>5) + e][l&31]
//   C/D   : lane holds C[(r&3) + 8*(r>>2) + 4*(l>>5)][l&31], r=0..15
__global__ __launch_bounds__(64, 2) void lqr_kernel(
    const float* __restrict__ gA,   // [B,32,32]
    const float* __restrict__ gB,   // [B,32,8]
    const float* __restrict__ gQ,   // [B,32,32]
    const float* __restrict__ gR,   // [B,8,8]
    const float* __restrict__ gG,   // [B,201,32]
    float* __restrict__ outK,       // [T,B,8,32]
    float* __restrict__ outk)       // [T,B,8]
{
    __shared__ __attribute__((aligned(16))) float smem[4008];
    float* const sA   = smem;          // [32][32] row-major
    float* const sW   = smem + 1024;   // [32][33] W=A^T V, pad 33
    float* const sABK = smem + 2080;   // [32][32] A - B*Kg
    float* const sBp  = smem + 3104;   // [32][9]  B padded
    float* const sBtV = smem + 3392;   // [8][36]  B^T V; aliased as Kg after P2
    float* const sM2  = smem + 3680;   // [8][36]  BtV*A
    float* const svv  = smem + 3968;   // [32] running v
    float* const sbtv = smem + 4000;   // [8]  B^T v

    const int lane = threadIdx.x;
    const int b    = blockIdx.x;
    const int ig   = lane >> 3;        // 0..7
    const int kg   = lane & 7;         // 0..7
    const int i0   = ig << 2;
    const int k0   = kg << 2;
    const int jj   = lane & 31;
    const int col  = lane & 31;        // MFMA row/col within tile
    const int up   = lane >> 5;        // 0/1: lane-half

    const float* __restrict__ Ab = gA + (size_t)b * 1024;
    const float* __restrict__ Bb = gB + (size_t)b * 256;
    const float* __restrict__ Qb = gQ + (size_t)b * 1024;
    const float* __restrict__ Gb = gG + (size_t)b * (201 * 32);

    // ---------------- one-time staging ----------------
    #pragma unroll
    for (int m = 0; m < 4; ++m)
        reinterpret_cast<float4*>(sA)[lane + 64 * m] =
            reinterpret_cast<const float4*>(Ab)[lane + 64 * m];
    {
        float4 b4 = reinterpret_cast<const float4*>(Bb)[lane];
        const int fb = lane * 4;
        sBp[((fb + 0) >> 3) * 9 + ((fb + 0) & 7)] = b4.x;
        sBp[((fb + 1) >> 3) * 9 + ((fb + 1) & 7)] = b4.y;
        sBp[((fb + 2) >> 3) * 9 + ((fb + 2) & 7)] = b4.z;
        sBp[((fb + 3) >> 3) * 9 + ((fb + 3) & 7)] = b4.w;
    }
    const float rreg = gR[(size_t)b * 64 + lane];   // R[ig][kg]

    // A^T as MFMA A-operand (fixed): At[row][k] = A[k][row]
    Frag3 AtF[2];
    #pragma unroll
    for (int h = 0; h < 2; ++h) {
        float f[8];
        #pragma unroll
        for (int e = 0; e < 8; ++e) f[e] = Ab[(16 * h + 8 * up + e) * 32 + col];
        AtF[h] = split3_8(f);
    }
    // B^T zero-padded to 32x32 as MFMA A-operand (fixed): rows 8..31 = 0
    Frag3 BtF[2];
    #pragma unroll
    for (int h = 0; h < 2; ++h) {
        float f[8];
        #pragma unroll
        for (int e = 0; e < 8; ++e)
            f[e] = (col < 8) ? Bb[(16 * h + 8 * up + e) * 8 + col] : 0.f;
        BtF[h] = split3_8(f);
    }
    // Q in C/D layout (epilogue addend of P5) + Q columns for Q*goal (Q symmetric)
    f32x16 qfr;
    #pragma unroll
    for (int r = 0; r < 16; ++r)
        qfr[r] = Qb[((r & 3) + 8 * (r >> 2) + 4 * up) * 32 + col];
    float Qcol[32];
    #pragma unroll
    for (int m = 0; m < 32; ++m) Qcol[m] = Qb[m * 32 + jj];

    {   // v0 = Q * goals[:, T, :]
        const float* __restrict__ gl = Gb + 200 * 32;
        float t = 0.f;
        #pragma unroll
        for (int m = 0; m < 32; ++m) t += Qcol[m] * gl[m];
        if (lane < 32) svv[jj] = t;
    }

    f32x16 vacc = qfr;   // V0 = Q, held in C/D layout across steps

    for (int c = 0; c < NT; ++c) {
        const int step = NT - 1 - c;
        const float* __restrict__ grow = Gb + step * 32;

        float t2 = 0.f;
        #pragma unroll
        for (int m = 0; m < 32; ++m) t2 += Qcol[m] * grow[m];

        // ---- V (C/D regs) -> B-operand frags, via lane-half exchange
        float sw[16];
        #pragma unroll
        for (int r = 0; r < 16; ++r) sw[r] = __shfl_xor(vacc[r], 32, 64);
        Frag3 VF[2];
        {
            float f[8];
            #pragma unroll
            for (int e = 0; e < 4; ++e) f[e]     = up ? sw[4 + e]    : vacc[e];
            #pragma unroll
            for (int e = 0; e < 4; ++e) f[4 + e] = up ? vacc[4 + e]  : sw[e];
            VF[0] = split3_8(f);
            #pragma unroll
            for (int e = 0; e < 4; ++e) f[e]     = up ? sw[12 + e]   : vacc[8 + e];
            #pragma unroll
            for (int e = 0; e < 4; ++e) f[4 + e] = up ? vacc[12 + e] : sw[8 + e];
            VF[1] = split3_8(f);
        }

        // ---- P1 (MFMA): W = A^T V (2-acc grouped); BtV = (B^T pad) V (1-acc,
        //      small-first from 0 — BtV is recomputed fresh each step and its
        //      error passes only through Vuu^-1 (||.||<=1), not the recursion)
        f32x16 wC, wB, bacc;
        #pragma unroll
        for (int r = 0; r < 16; ++r) { wC[r] = 0.f; wB[r] = 0.f; bacc[r] = 0.f; }
        wC = mm_lo(wC, AtF[0], VF[0]);
        wC = mm_lo(wC, AtF[1], VF[1]);
        wB = mm_hh(wB, AtF[0], VF[0]);
        wB = mm_hh(wB, AtF[1], VF[1]);
        bacc = mm_lo(bacc, BtF[0], VF[0]);
        bacc = mm_lo(bacc, BtF[1], VF[1]);
        bacc = mm_hh(bacc, BtF[0], VF[0]);
        bacc = mm_hh(bacc, BtF[1], VF[1]);

        #pragma unroll
        for (int r = 0; r < 16; ++r)
            sW[((r & 3) + 8 * (r >> 2) + 4 * up) * 33 + col] = wC[r] + wB[r];
        #pragma unroll
        for (int r = 0; r < 4; ++r)
            sBtV[(r + 4 * up) * 36 + col] = bacc[r];

        // ---- btv[u] = sum_j B[j][u] * v[j]  (8-lane-group reduce)
        {
            const int u = lane & 7, q = lane >> 3;
            float p = 0.f;
            #pragma unroll
            for (int j = 0; j < 4; ++j) p += sBp[(4 * q + j) * 9 + u] * svv[4 * q + j];
            p += __shfl_xor(p, 8, 64);
            p += __shfl_xor(p, 16, 64);
            p += __shfl_xor(p, 32, 64);
            if (lane < 8) sbtv[u] = p;
        }

        // ---- P2 (VALU): M2 = BtV*A ; Vuu = BtV*B + R (fused)
        float cur, cur8;
        {
            float m20 = 0, m21 = 0, m22 = 0, m23 = 0, vu = rreg;
            #pragma unroll
            for (int j = 0; j < 32; ++j) {
                const float  btvj = sBtV[ig * 36 + j];
                const float4 a4   = *reinterpret_cast<const float4*>(&sA[j * 32 + k0]);
                const float  bk   = sBp[j * 9 + kg];
                m20 += btvj * a4.x; m21 += btvj * a4.y;
                m22 += btvj * a4.z; m23 += btvj * a4.w;
                vu  += btvj * bk;
            }
            *reinterpret_cast<float4*>(&sM2[ig * 36 + k0]) = make_float4(m20, m21, m22, m23);
            cur  = vu;
            cur8 = (ig == kg) ? 1.f : 0.f;
        }

        // ---- Gauss-Jordan inverse of Vuu, fully in registers via shfl.
        // Lane (ig,kg) holds [Vuu|I][ig][kg]. PD with diag>=1 -> no pivoting.
        #pragma unroll
        for (int p = 0; p < 8; ++p) {
            const float piv = __shfl(cur, p * 8 + p, 64);
            const float rp  = 1.0f / piv;
            const float pc  = __shfl(cur,  p * 8 + kg, 64);
            const float pc8 = __shfl(cur8, p * 8 + kg, 64);
            const float mrp = __shfl(cur,  ig * 8 + p, 64);
            const float fgj = mrp * rp;
            const bool  isp = (ig == p);
            cur  = isp ? pc  * rp : cur  - fgj * pc;
            cur8 = isp ? pc8 * rp : cur8 - fgj * pc8;
        }

        // ---- P3: Kg = Vuu_inv * M2 ; kf = Vuu_inv * (B^T v) ; write outputs
        float* const sKg = sBtV;   // BtV dead after P2
        {
            float ka0 = 0, ka1 = 0, ka2 = 0, ka3 = 0, kfv = 0;
            #pragma unroll
            for (int u2 = 0; u2 < 8; ++u2) {
                const float  w  = __shfl(cur8, ig * 8 + u2, 64);   // inv[ig][u2]
                const float4 m4 = *reinterpret_cast<const float4*>(&sM2[u2 * 36 + k0]);
                const float  bt = sbtv[u2];
                ka0 += w * m4.x; ka1 += w * m4.y; ka2 += w * m4.z; ka3 += w * m4.w;
                kfv += w * bt;
            }
            *reinterpret_cast<float4*>(&sKg[ig * 36 + k0]) = make_float4(ka0, ka1, ka2, ka3);
            const size_t ob = (size_t)step * NBATCH + b;
            *reinterpret_cast<float4*>(&outK[ob * 256 + ig * 32 + k0]) =
                make_float4(ka0, ka1, ka2, ka3);
            if (kg == 0) outk[ob * 8 + ig] = kfv;
        }

        // ---- P4 (VALU): ABK = A - B*Kg
        {
            const float4 a0 = *reinterpret_cast<const float4*>(&sA[(i0 + 0) * 32 + k0]);
            const float4 a1 = *reinterpret_cast<const float4*>(&sA[(i0 + 1) * 32 + k0]);
            const float4 a2 = *reinterpret_cast<const float4*>(&sA[(i0 + 2) * 32 + k0]);
            const float4 a3 = *reinterpret_cast<const float4*>(&sA[(i0 + 3) * 32 + k0]);
            float b00=a0.x,b01=a0.y,b02=a0.z,b03=a0.w;
            float b10=a1.x,b11=a1.y,b12=a1.z,b13=a1.w;
            float b20=a2.x,b21=a2.y,b22=a2.z,b23=a2.w;
            float b30=a3.x,b31=a3.y,b32=a3.z,b33=a3.w;
            #pragma unroll
            for (int u = 0; u < 8; ++u) {
                const float4 kg4 = *reinterpret_cast<const float4*>(&sKg[u * 36 + k0]);
                const float br0 = sBp[(i0 + 0) * 9 + u];
                const float br1 = sBp[(i0 + 1) * 9 + u];
                const float br2 = sBp[(i0 + 2) * 9 + u];
                const float br3 = sBp[(i0 + 3) * 9 + u];
                b00 -= br0*kg4.x; b01 -= br0*kg4.y; b02 -= br0*kg4.z; b03 -= br0*kg4.w;
                b10 -= br1*kg4.x; b11 -= br1*kg4.y; b12 -= br1*kg4.z; b13 -= br1*kg4.w;
                b20 -= br2*kg4.x; b21 -= br2*kg4.y; b22 -= br2*kg4.z; b23 -= br2*kg4.w;
                b30 -= br3*kg4.x; b31 -= br3*kg4.y; b32 -= br3*kg4.z; b33 -= br3*kg4.w;
            }
            *reinterpret_cast<float4*>(&sABK[(i0 + 0) * 32 + k0]) = make_float4(b00, b01, b02, b03);
            *reinterpret_cast<float4*>(&sABK[(i0 + 1) * 32 + k0]) = make_float4(b10, b11, b12, b13);
            *reinterpret_cast<float4*>(&sABK[(i0 + 2) * 32 + k0]) = make_float4(b20, b21, b22, b23);
            *reinterpret_cast<float4*>(&sABK[(i0 + 3) * 32 + k0]) = make_float4(b30, b31, b32, b33);
        }

        // ---- build P5 operand frags: W as A-op, ABK as B-op
        Frag3 WF[2], KF[2];
        #pragma unroll
        for (int h = 0; h < 2; ++h) {
            float f[8];
            #pragma unroll
            for (int e = 0; e < 8; ++e) f[e] = sABK[(16 * h + 8 * up + e) * 32 + col];
            KF[h] = split3_8(f);
        }
        #pragma unroll
        for (int h = 0; h < 2; ++h) {
            float f[8];
            #pragma unroll
            for (int e = 0; e < 8; ++e) f[e] = sW[col * 33 + 16 * h + 8 * up + e];
            WF[h] = split3_8(f);
        }

        // ---- P5 (MFMA): V_new = W*ABK + Q, 2-acc grouped; Q added LAST in
        //      VALU so no MFMA call rounds small terms against |Q|-sized acc.
        {
            f32x16 vC, vB;
            #pragma unroll
            for (int r = 0; r < 16; ++r) { vC[r] = 0.f; vB[r] = 0.f; }
            vC = mm_lo(vC, WF[0], KF[0]);
            vC = mm_lo(vC, WF[1], KF[1]);
            vB = mm_hh(vB, WF[0], KF[0]);
            vB = mm_hh(vB, WF[1], KF[1]);
            #pragma unroll
            for (int r = 0; r < 16; ++r) vacc[r] = (vC[r] + vB[r]) + qfr[r];
        }

        // ---- v_new = ABK^T v + Q*goal
        {
            float t1 = 0.f;
            #pragma unroll
            for (int m = 0; m < 32; ++m) t1 += sABK[m * 32 + jj] * svv[m];
            if (lane < 32) svv[jj] = t1 + t2;
        }
    }
}

}  // namespace

extern "C" void kernel_launch(void* const* d_in, const int* in_sizes, int n_in,
                              void* d_out, int out_size, void* d_ws, size_t ws_size,
                              hipStream_t stream) {
    const float* A = (const float*)d_in[0];
    const float* B = (const float*)d_in[1];
    const float* Q = (const float*)d_in[2];
    const float* R = (const float*)d_in[3];
    const float* G = (const float*)d_in[4];
    float* outK = (float*)d_out;
    float* outk = outK + (size_t)NT * NBATCH * 8 * 32;
    lqr_kernel<<<dim3(NBATCH), dim3(64), 0, stream>>>(A, B, Q, R, G, outK, outk);
}